// Round 2
// baseline (21232.178 us; speedup 1.0000x reference)
//
#include <hip/hip_runtime.h>
#include <math.h>

typedef _Float16 f16;
typedef f16 half8 __attribute__((ext_vector_type(8)));
typedef float f32x4 __attribute__((ext_vector_type(4)));

#define NBATCH 64
#define NTIME  512
#define NU     1024
#define NE     256
#define NVOCAB 32000

// ---------------- ws layout (bytes) ----------------
// emb16 : 0           16,384,000   (32000*256 f16)
// hf32  : 16,384,000     262,144   (64*1024 f32)
// hf16  : 16,646,144     131,072   (64*1024 f16)
// rh16  : 16,777,216     131,072   (64*1024 f16)
// zbuf  : 16,908,288     262,144   (64*1024 f32)
// zhbuf : 17,170,432     262,144   (64*1024 f32)
// flags : 17,432,576       1,024   (256 int)
#define OFF_EMB16 0
#define OFF_HF32  16384000
#define OFF_HF16  16646144
#define OFF_RH16  16777216
#define OFF_ZBUF  16908288
#define OFF_ZHBUF 17170432
#define OFF_FLAGS 17432576

__global__ void prep_kernel(const float* __restrict__ emb, const float* __restrict__ hid,
                            f16* __restrict__ emb16, float* __restrict__ hf32,
                            f16* __restrict__ hf16, int* __restrict__ flags)
{
    int stride = gridDim.x * blockDim.x;
    int t0 = blockIdx.x * blockDim.x + threadIdx.x;
    for (int i = t0; i < NVOCAB * NE; i += stride) emb16[i] = (f16)emb[i];
    for (int i = t0; i < NBATCH * NU; i += stride) { float v = hid[i]; hf32[i] = v; hf16[i] = (f16)v; }
    if (t0 < 256) flags[t0] = 0;
}

__device__ __forceinline__ void st_agent_f32(float* p, float v) {
    __hip_atomic_store(p, v, __ATOMIC_RELAXED, __HIP_MEMORY_SCOPE_AGENT);
}
__device__ __forceinline__ void st_agent_f16(f16* p, f16 v) {
    union { f16 h; unsigned short u; } cv; cv.h = v;
    __hip_atomic_store((unsigned short*)p, cv.u, __ATOMIC_RELAXED, __HIP_MEMORY_SCOPE_AGENT);
}

// 192 workgroups x 256 threads, persistent.
// wg [0,64)   : A-role, z columns  [wg*16, wg*16+16)
// wg [64,128) : A-role, r columns  [wg*16, wg*16+16)   (global col 1024..2048)
// wg [128,192): B-role, hh columns [2048+(wg-128)*16, ...)
__global__ __launch_bounds__(256)
void scan_kernel(const int* __restrict__ x, const float* __restrict__ rk,
                 const float* __restrict__ kw, const float* __restrict__ bias,
                 const f16* __restrict__ emb16,
                 float* __restrict__ hf32, f16* __restrict__ hf16, f16* __restrict__ rh16,
                 float* __restrict__ zbuf, float* __restrict__ zhbuf,
                 int* __restrict__ flags, float* __restrict__ out)
{
    __shared__ char lds[40960];   // [0,32768): W slice 16x1024 f16 ; [32768,40960): K slice 16x256 f16

    const int wg   = blockIdx.x;
    const int tid  = threadIdx.x;
    const int lane = tid & 63;
    const int wv   = tid >> 6;
    const bool isB = (wg >= 128);
    const int col0 = isB ? (2048 + (wg - 128) * 16) : (wg * 16);

    // ---- one-time LDS staging of weight column-slices (f32 -> f16, XOR-swizzled [c][k]) ----
    for (int idx = tid; idx < 16 * 1024; idx += 256) {
        int c = idx & 15, k = idx >> 4;
        f16 v = (f16)rk[k * 3072 + col0 + c];
        *(f16*)(lds + c * 2048 + ((k * 2) ^ ((c & 7) << 4))) = v;
    }
    for (int idx = tid; idx < 16 * 256; idx += 256) {
        int c = idx & 15, k = idx >> 4;
        f16 v = (f16)kw[k * 3072 + col0 + c];
        *(f16*)(lds + 32768 + c * 512 + ((k * 2) ^ ((c & 7) << 4))) = v;
    }
    __syncthreads();

    const float bias_v = bias[col0 + (lane & 15)];
    const int arow  = 16 * wv + (lane & 15);    // A-fragment row (batch index)
    const int aoff  = 8 * (lane >> 4);          // k sub-offset within 32-chunk
    const int drow0 = 16 * wv + 4 * (lane >> 4);// D rows = drow0 + reg
    const int dcol  = col0 + (lane & 15);       // global output column
    const int wbyte = (lane & 15) * 2048;
    const int kbyte = 32768 + (lane & 15) * 512;
    const int swz   = (lane & 7) << 4;

    int* aflags = flags;        // 128 entries
    int* bflags = flags + 128;  // 64 entries

    for (int t = 0; t < NTIME; ++t) {
        // ---------- x-part (independent of h): emb[x[b,t]] @ kernel[:, cols] ----------
        f32x4 acc0 = {0.f, 0.f, 0.f, 0.f}, acc1 = {0.f, 0.f, 0.f, 0.f};
        {
            const int xid = x[arow * NTIME + t];
            const f16* ep = emb16 + (size_t)xid * NE + aoff;
#pragma unroll
            for (int kk = 0; kk < NE; kk += 64) {
                half8 a0 = *(const half8*)(ep + kk);
                half8 b0 = *(const half8*)(lds + kbyte + (((kk + aoff) * 2) ^ swz));
                acc0 = __builtin_amdgcn_mfma_f32_16x16x32_f16(a0, b0, acc0, 0, 0, 0);
                half8 a1 = *(const half8*)(ep + kk + 32);
                half8 b1 = *(const half8*)(lds + kbyte + (((kk + 32 + aoff) * 2) ^ swz));
                acc1 = __builtin_amdgcn_mfma_f32_16x16x32_f16(a1, b1, acc1, 0, 0, 0);
            }
        }

        // ---------- wait for producer ----------
        if (tid < 64) {
            if (!isB) {
                for (;;) {
                    int v = __hip_atomic_load(&bflags[lane], __ATOMIC_RELAXED, __HIP_MEMORY_SCOPE_AGENT);
                    if (__all(v >= t)) break;
                    __builtin_amdgcn_s_sleep(1);
                }
            } else {
                for (;;) {
                    int v0 = __hip_atomic_load(&aflags[lane], __ATOMIC_RELAXED, __HIP_MEMORY_SCOPE_AGENT);
                    int v1 = __hip_atomic_load(&aflags[lane + 64], __ATOMIC_RELAXED, __HIP_MEMORY_SCOPE_AGENT);
                    if (__all((v0 >= t + 1) && (v1 >= t + 1))) break;
                    __builtin_amdgcn_s_sleep(1);
                }
            }
            __threadfence();   // acquire: invalidate stale L1/L2 before reading h / rh / z
        }
        __syncthreads();

        // ---------- recurrent part: (h or r*h) @ rk[:, cols] ----------
        {
            const f16* ap = (isB ? rh16 : hf16) + arow * NU + aoff;
#pragma unroll 4
            for (int kk = 0; kk < NU; kk += 64) {
                half8 a0 = *(const half8*)(ap + kk);
                half8 b0 = *(const half8*)(lds + wbyte + (((kk + aoff) * 2) ^ swz));
                acc0 = __builtin_amdgcn_mfma_f32_16x16x32_f16(a0, b0, acc0, 0, 0, 0);
                half8 a1 = *(const half8*)(ap + kk + 32);
                half8 b1 = *(const half8*)(lds + wbyte + (((kk + 32 + aoff) * 2) ^ swz));
                acc1 = __builtin_amdgcn_mfma_f32_16x16x32_f16(a1, b1, acc1, 0, 0, 0);
            }
        }
        f32x4 acc = acc0 + acc1;

        // ---------- gates / state update ----------
        if (!isB) {
            if (col0 < 1024) {            // z role
#pragma unroll
                for (int i = 0; i < 4; ++i) {
                    int b = drow0 + i;
                    float s = acc[i] + bias_v;
                    float z = 1.f / (1.f + exp2f(-1.4426950408889634f * s));
                    float h = hf32[b * NU + dcol];
                    st_agent_f32(&zbuf[b * NU + dcol], z);
                    st_agent_f32(&zhbuf[b * NU + dcol], z * h);
                }
            } else {                      // r role
                int jr = dcol - 1024;
#pragma unroll
                for (int i = 0; i < 4; ++i) {
                    int b = drow0 + i;
                    float s = acc[i] + bias_v;
                    float r = 1.f / (1.f + exp2f(-1.4426950408889634f * s));
                    float h = hf32[b * NU + jr];
                    st_agent_f16(&rh16[b * NU + jr], (f16)(r * h));
                }
            }
        } else {                          // B role: hh, h_next, outputs
            int jh = dcol - 2048;
#pragma unroll
            for (int i = 0; i < 4; ++i) {
                int b = drow0 + i;
                float s = acc[i] + bias_v;
                float e = exp2f(2.8853900817779268f * s);
                float hh = 1.f - 2.f / (e + 1.f);     // tanh(s), inf-safe
                float z = zbuf[b * NU + jh];
                float hn = zhbuf[b * NU + jh] + (1.f - z) * hh;
                __builtin_nontemporal_store(hn, &out[(size_t)b * (NTIME * NU) + (size_t)t * NU + jh]);
                st_agent_f32(&hf32[b * NU + jh], hn);
                st_agent_f16(&hf16[b * NU + jh], (f16)hn);
                if (t == NTIME - 1)
                    __builtin_nontemporal_store(hn, &out[(size_t)NBATCH * NTIME * NU + b * NU + jh]);
            }
        }

        __threadfence();      // release: make this WG's writes agent-visible
        __syncthreads();
        if (tid == 0)
            __hip_atomic_store(&flags[wg], t + 1, __ATOMIC_RELEASE, __HIP_MEMORY_SCOPE_AGENT);
    }
}

extern "C" void kernel_launch(void* const* d_in, const int* in_sizes, int n_in,
                              void* d_out, int out_size, void* d_ws, size_t ws_size,
                              hipStream_t stream)
{
    const int*   x    = (const int*)d_in[0];
    const float* hid  = (const float*)d_in[1];
    const float* emb  = (const float*)d_in[2];
    const float* kw   = (const float*)d_in[3];
    const float* rk   = (const float*)d_in[4];
    const float* bias = (const float*)d_in[5];

    char* ws = (char*)d_ws;
    f16*   emb16 = (f16*)  (ws + OFF_EMB16);
    float* hf32  = (float*)(ws + OFF_HF32);
    f16*   hf16  = (f16*)  (ws + OFF_HF16);
    f16*   rh16  = (f16*)  (ws + OFF_RH16);
    float* zbuf  = (float*)(ws + OFF_ZBUF);
    float* zhbuf = (float*)(ws + OFF_ZHBUF);
    int*   flags = (int*)  (ws + OFF_FLAGS);
    float* out   = (float*)d_out;

    prep_kernel<<<2048, 256, 0, stream>>>(emb, hid, emb16, hf32, hf16, flags);
    scan_kernel<<<192, 256, 0, stream>>>(x, rk, kw, bias, emb16,
                                         hf32, hf16, rh16, zbuf, zhbuf, flags, out);
}

// Round 3
// 9199.123 us; speedup vs baseline: 2.3081x; 2.3081x over previous
//
#include <hip/hip_runtime.h>
#include <math.h>

typedef _Float16 f16;
typedef f16 half8 __attribute__((ext_vector_type(8)));
typedef f16 half4 __attribute__((ext_vector_type(4)));
typedef float f32x4 __attribute__((ext_vector_type(4)));

#define NBATCH 64
#define NTIME  512
#define NU     1024
#define NE     256
#define NVOCAB 32000

// ---------------- ws layout (bytes) ----------------
// emb16 : 0           16,384,000
// hf16  : 16,384,000     131,072
// rh16  : 16,515,072     131,072
// zbuf  : 16,646,144     262,144
// flags : 16,908,288         512   (128 int)
#define OFF_EMB16 0
#define OFF_HF16  16384000
#define OFF_RH16  16515072
#define OFF_ZBUF  16646144
#define OFF_FLAGS 16908288

#define MFMA16 __builtin_amdgcn_mfma_f32_16x16x32_f16

__global__ void prep_kernel(const float* __restrict__ emb, const float* __restrict__ hid,
                            f16* __restrict__ emb16, f16* __restrict__ hf16,
                            int* __restrict__ flags)
{
    int stride = gridDim.x * blockDim.x;
    int t0 = blockIdx.x * blockDim.x + threadIdx.x;
    for (int i = t0; i < NVOCAB * NE / 4; i += stride) {
        float4 v = ((const float4*)emb)[i];
        half4 h; h[0] = (f16)v.x; h[1] = (f16)v.y; h[2] = (f16)v.z; h[3] = (f16)v.w;
        ((half4*)emb16)[i] = h;
    }
    for (int i = t0; i < NBATCH * NU; i += stride) hf16[i] = (f16)hid[i];
    if (t0 < 128) flags[t0] = 0;
}

// ---- per-access coherent (MALL-level) memory ops: sc0 sc1 bypass non-coherent L1/L2 ----
__device__ __forceinline__ half8 ld_cc_b128(const f16* p) {
    half8 v;
    asm volatile("global_load_dwordx4 %0, %1, off sc0 sc1" : "=v"(v) : "v"(p));
    return v;   // caller must s_waitcnt vmcnt before use
}
__device__ __forceinline__ unsigned ld_cc_u16(const f16* p) {
    unsigned v;
    asm volatile("global_load_ushort %0, %1, off sc0 sc1" : "=v"(v) : "v"(p));
    return v;
}
__device__ __forceinline__ float ld_cc_f32(const float* p) {
    float v;
    asm volatile("global_load_dword %0, %1, off sc0 sc1" : "=v"(v) : "v"(p));
    return v;
}
__device__ __forceinline__ void st_cc_f32(float* p, float v) {
    asm volatile("global_store_dword %0, %1, off sc0 sc1" :: "v"(p), "v"(v));
}
__device__ __forceinline__ void st_cc_u16(f16* p, unsigned v) {
    asm volatile("global_store_short %0, %1, off sc0 sc1" :: "v"(p), "v"(v));
}
__device__ __forceinline__ void st_cc_i32(int* p, int v) {
    asm volatile("global_store_dword %0, %1, off sc0 sc1" :: "v"(p), "v"(v));
}
__device__ __forceinline__ void drain_vm() {
    asm volatile("s_waitcnt vmcnt(0)" ::: "memory");
    __builtin_amdgcn_sched_barrier(0);   // rule #18: stop MFMA hoisting past the waitcnt
}

// 128 persistent WGs x 256 threads, 1 WG/CU.
// wg [0,64)  : A-role — z AND r gates for cols [wg*16, wg*16+16)   (shared h A-operand)
// wg [64,128): B-role — hh + state update for cols [(wg-64)*16, ...)
__global__ __launch_bounds__(256, 1)
void scan_kernel(const int* __restrict__ x, const float* __restrict__ rk,
                 const float* __restrict__ kw, const float* __restrict__ bias,
                 const f16* __restrict__ emb16, const float* __restrict__ hid,
                 f16* __restrict__ hf16, f16* __restrict__ rh16, float* __restrict__ zbuf,
                 int* __restrict__ flags, float* __restrict__ out)
{
    __shared__ char lds[81920];  // A: Wz[0,32K) Wr[32K,64K) Kz[64K,72K) Kr[72K,80K); B: Wh[0,32K) Kh[64K,72K)

    const int wg = blockIdx.x, tid = threadIdx.x, lane = tid & 63, wv = tid >> 6;
    const bool isB = wg >= 64;
    const int c0 = (isB ? wg - 64 : wg) * 16;

    // ---- one-time LDS staging (f32 -> f16, XOR-swizzled [c][k]) ----
    if (!isB) {
        for (int idx = tid; idx < 16 * 1024; idx += 256) {
            int c = idx & 15, k = idx >> 4, sw = (k * 2) ^ ((c & 7) << 4);
            *(f16*)(lds + c * 2048 + sw)         = (f16)rk[k * 3072 + c0 + c];
            *(f16*)(lds + 32768 + c * 2048 + sw) = (f16)rk[k * 3072 + 1024 + c0 + c];
        }
        for (int idx = tid; idx < 16 * 256; idx += 256) {
            int c = idx & 15, k = idx >> 4, sw = (k * 2) ^ ((c & 7) << 4);
            *(f16*)(lds + 65536 + c * 512 + sw) = (f16)kw[k * 3072 + c0 + c];
            *(f16*)(lds + 73728 + c * 512 + sw) = (f16)kw[k * 3072 + 1024 + c0 + c];
        }
    } else {
        for (int idx = tid; idx < 16 * 1024; idx += 256) {
            int c = idx & 15, k = idx >> 4, sw = (k * 2) ^ ((c & 7) << 4);
            *(f16*)(lds + c * 2048 + sw) = (f16)rk[k * 3072 + 2048 + c0 + c];
        }
        for (int idx = tid; idx < 16 * 256; idx += 256) {
            int c = idx & 15, k = idx >> 4, sw = (k * 2) ^ ((c & 7) << 4);
            *(f16*)(lds + 65536 + c * 512 + sw) = (f16)kw[k * 3072 + 2048 + c0 + c];
        }
    }
    __syncthreads();

    const int arow  = 16 * wv + (lane & 15);     // A-fragment row (batch)
    const int aoff  = 8 * (lane >> 4);           // k sub-offset
    const int drow0 = 16 * wv + 4 * (lane >> 4); // D rows = drow0 + reg
    const int dc    = c0 + (lane & 15);          // column within gate
    const int swz   = (lane & 7) << 4;
    const int wb0   = (lane & 15) * 2048;
    const int wb1   = 32768 + (lane & 15) * 2048;
    const int kb0   = 65536 + (lane & 15) * 512;
    const int kb1   = 73728 + (lane & 15) * 512;

    int* aflags = flags;
    int* bflags = flags + 64;

    if (!isB) {
        const float bz = bias[dc], br = bias[1024 + dc];
        for (int t = 0; t < NTIME; ++t) {
            // x-part (h-independent): overlaps producer phase
            f32x4 accz = {0, 0, 0, 0}, accr = {0, 0, 0, 0};
            {
                const int xid = x[arow * NTIME + t];
                const f16* ep = emb16 + (size_t)xid * NE + aoff;
#pragma unroll
                for (int kk = 0; kk < NE; kk += 64) {
                    half8 a0 = *(const half8*)(ep + kk);
                    half8 a1 = *(const half8*)(ep + kk + 32);
                    accz = MFMA16(a0, *(half8*)(lds + kb0 + (((kk + aoff) * 2) ^ swz)), accz, 0, 0, 0);
                    accr = MFMA16(a0, *(half8*)(lds + kb1 + (((kk + aoff) * 2) ^ swz)), accr, 0, 0, 0);
                    accz = MFMA16(a1, *(half8*)(lds + kb0 + (((kk + 32 + aoff) * 2) ^ swz)), accz, 0, 0, 0);
                    accr = MFMA16(a1, *(half8*)(lds + kb1 + (((kk + 32 + aoff) * 2) ^ swz)), accr, 0, 0, 0);
                }
            }
            if (tid < 64) {   // wait: B finished step t-1 -> h_t visible, old z/rh consumed
                for (;;) {
                    int v = __hip_atomic_load(&bflags[lane], __ATOMIC_RELAXED, __HIP_MEMORY_SCOPE_AGENT);
                    if (__all(v >= t)) break;
                    __builtin_amdgcn_s_sleep(1);
                }
            }
            __syncthreads();
            __builtin_amdgcn_sched_barrier(0);

            const f16* hp = hf16 + arow * NU + aoff;
            half8 ha[16], hb[16];
#pragma unroll
            for (int i = 0; i < 16; ++i) { ha[i] = ld_cc_b128(hp + 64 * i); hb[i] = ld_cc_b128(hp + 64 * i + 32); }
            unsigned hs[4];
#pragma unroll
            for (int i = 0; i < 4; ++i) hs[i] = ld_cc_u16(hf16 + (drow0 + i) * NU + dc);
            drain_vm();
#pragma unroll
            for (int i = 0; i < 16; ++i) {
                int kk = 64 * i;
                accz = MFMA16(ha[i], *(half8*)(lds + wb0 + (((kk + aoff) * 2) ^ swz)), accz, 0, 0, 0);
                accr = MFMA16(ha[i], *(half8*)(lds + wb1 + (((kk + aoff) * 2) ^ swz)), accr, 0, 0, 0);
                accz = MFMA16(hb[i], *(half8*)(lds + wb0 + (((kk + 32 + aoff) * 2) ^ swz)), accz, 0, 0, 0);
                accr = MFMA16(hb[i], *(half8*)(lds + wb1 + (((kk + 32 + aoff) * 2) ^ swz)), accr, 0, 0, 0);
            }
#pragma unroll
            for (int i = 0; i < 4; ++i) {
                int b = drow0 + i;
                float z = 1.f / (1.f + exp2f(-1.4426950408889634f * (accz[i] + bz)));
                st_cc_f32(&zbuf[b * NU + dc], z);
                float r = 1.f / (1.f + exp2f(-1.4426950408889634f * (accr[i] + br)));
                union { unsigned short u; f16 h; } cv; cv.u = (unsigned short)hs[i];
                union { f16 h; unsigned short u; } cw; cw.h = (f16)(r * (float)cv.h);
                st_cc_u16(&rh16[b * NU + dc], (unsigned)cw.u);
            }
            asm volatile("s_waitcnt vmcnt(0)" ::: "memory");  // stores at coherent point
            __syncthreads();
            if (tid == 0) st_cc_i32(&aflags[wg], t + 1);
        }
    } else {
        const float bh = bias[2048 + dc];
        float hprev[4];
#pragma unroll
        for (int i = 0; i < 4; ++i) hprev[i] = hid[(drow0 + i) * NU + dc];  // own cols stay in regs
        for (int t = 0; t < NTIME; ++t) {
            f32x4 acc0 = {0, 0, 0, 0}, acc1 = {0, 0, 0, 0};
            {
                const int xid = x[arow * NTIME + t];
                const f16* ep = emb16 + (size_t)xid * NE + aoff;
#pragma unroll
                for (int kk = 0; kk < NE; kk += 64) {
                    half8 a0 = *(const half8*)(ep + kk);
                    half8 a1 = *(const half8*)(ep + kk + 32);
                    acc0 = MFMA16(a0, *(half8*)(lds + kb0 + (((kk + aoff) * 2) ^ swz)), acc0, 0, 0, 0);
                    acc1 = MFMA16(a1, *(half8*)(lds + kb0 + (((kk + 32 + aoff) * 2) ^ swz)), acc1, 0, 0, 0);
                }
            }
            if (tid < 64) {   // wait: all A done step t -> z/rh ready, h_t no longer read
                for (;;) {
                    int v = __hip_atomic_load(&aflags[lane], __ATOMIC_RELAXED, __HIP_MEMORY_SCOPE_AGENT);
                    if (__all(v >= t + 1)) break;
                    __builtin_amdgcn_s_sleep(1);
                }
            }
            __syncthreads();
            __builtin_amdgcn_sched_barrier(0);

            const f16* rp = rh16 + arow * NU + aoff;
            half8 ra[16], rb[16];
#pragma unroll
            for (int i = 0; i < 16; ++i) { ra[i] = ld_cc_b128(rp + 64 * i); rb[i] = ld_cc_b128(rp + 64 * i + 32); }
            float zz[4];
#pragma unroll
            for (int i = 0; i < 4; ++i) zz[i] = ld_cc_f32(&zbuf[(drow0 + i) * NU + dc]);
            drain_vm();
#pragma unroll
            for (int i = 0; i < 16; ++i) {
                int kk = 64 * i;
                acc0 = MFMA16(ra[i], *(half8*)(lds + wb0 + (((kk + aoff) * 2) ^ swz)), acc0, 0, 0, 0);
                acc1 = MFMA16(rb[i], *(half8*)(lds + wb0 + (((kk + 32 + aoff) * 2) ^ swz)), acc1, 0, 0, 0);
            }
            f32x4 acc = acc0 + acc1;
#pragma unroll
            for (int i = 0; i < 4; ++i) {
                int b = drow0 + i;
                float s = acc[i] + bh;
                float e = exp2f(2.8853900817779268f * s);
                float hh = 1.f - 2.f / (e + 1.f);          // tanh(s), inf-safe
                float hn = zz[i] * hprev[i] + (1.f - zz[i]) * hh;
                hprev[i] = hn;
                __builtin_nontemporal_store(hn, &out[(size_t)b * (NTIME * NU) + (size_t)t * NU + dc]);
                union { f16 h; unsigned short u; } cw; cw.h = (f16)hn;
                st_cc_u16(&hf16[b * NU + dc], (unsigned)cw.u);
                if (t == NTIME - 1)
                    __builtin_nontemporal_store(hn, &out[(size_t)NBATCH * NTIME * NU + b * NU + dc]);
            }
            asm volatile("s_waitcnt vmcnt(0)" ::: "memory");
            __syncthreads();
            if (tid == 0) st_cc_i32(&bflags[wg - 64], t + 1);
        }
    }
}

extern "C" void kernel_launch(void* const* d_in, const int* in_sizes, int n_in,
                              void* d_out, int out_size, void* d_ws, size_t ws_size,
                              hipStream_t stream)
{
    const int*   x    = (const int*)d_in[0];
    const float* hid  = (const float*)d_in[1];
    const float* emb  = (const float*)d_in[2];
    const float* kw   = (const float*)d_in[3];
    const float* rk   = (const float*)d_in[4];
    const float* bias = (const float*)d_in[5];

    char* ws = (char*)d_ws;
    f16*   emb16 = (f16*)  (ws + OFF_EMB16);
    f16*   hf16  = (f16*)  (ws + OFF_HF16);
    f16*   rh16  = (f16*)  (ws + OFF_RH16);
    float* zbuf  = (float*)(ws + OFF_ZBUF);
    int*   flags = (int*)  (ws + OFF_FLAGS);
    float* out   = (float*)d_out;

    prep_kernel<<<2048, 256, 0, stream>>>(emb, hid, emb16, hf16, flags);
    scan_kernel<<<128, 256, 0, stream>>>(x, rk, kw, bias, emb16, hid,
                                         hf16, rh16, zbuf, flags, out);
}